// Round 1
// baseline (7081.261 us; speedup 1.0000x reference)
//
#include <hip/hip_runtime.h>

// SDGCN32: 31-layer GCN, N=100k nodes, E=3.2M edges, F=32.
// Strategy:
//  - hs = dis * h carried between layers; layer = gather(hs) -> *dis -> @W + b  (GEMM fused into gather kernel)
//  - CSR (by dst) built once per launch: histogram + scan + atomic-cursor fill
//  - output accumulated online: per layer j, out += mynorm(x_j) @ Mnorm_j (+ raw x_j @ W2block_j for j in {0,1,16})
//    Mnorm_j = [j>=2 && j!=16]*block_j - [j<=29 && j!=14]*block_{j+2}

__device__ __forceinline__ float shflx(float v, int m) { return __shfl_xor(v, m, 64); }

// ---------- CSR build ----------
__global__ void k_hist(const int* __restrict__ dst, int E, int* __restrict__ cnt) {
    int e = blockIdx.x * blockDim.x + threadIdx.x;
    if (e < E) atomicAdd(&cnt[dst[e]], 1);
}

__global__ void k_scan1(const int* __restrict__ cnt, int N, int* __restrict__ row_ptr,
                        int* __restrict__ bsums) {
    __shared__ int s[256];
    int i = blockIdx.x * 256 + threadIdx.x;
    int v = (i < N) ? cnt[i] : 0;
    s[threadIdx.x] = v;
    __syncthreads();
    for (int off = 1; off < 256; off <<= 1) {
        int t = (threadIdx.x >= off) ? s[threadIdx.x - off] : 0;
        __syncthreads();
        s[threadIdx.x] += t;
        __syncthreads();
    }
    int incl = s[threadIdx.x];
    if (i < N) row_ptr[i] = incl - v;           // exclusive within block
    if (threadIdx.x == 255) bsums[blockIdx.x] = incl;
}

__global__ void k_scan2(int* __restrict__ bsums, int nb) {
    __shared__ int s[512];
    int v = (threadIdx.x < nb) ? bsums[threadIdx.x] : 0;
    s[threadIdx.x] = v;
    __syncthreads();
    for (int off = 1; off < 512; off <<= 1) {
        int t = (threadIdx.x >= off) ? s[threadIdx.x - off] : 0;
        __syncthreads();
        s[threadIdx.x] += t;
        __syncthreads();
    }
    if (threadIdx.x < nb) bsums[threadIdx.x] = s[threadIdx.x] - v;  // exclusive
}

__global__ void k_scan3(int* __restrict__ row_ptr, const int* __restrict__ bsums,
                        const int* __restrict__ cnt, int N, int E,
                        int* __restrict__ cursor, float* __restrict__ dis) {
    int i = blockIdx.x * 256 + threadIdx.x;
    if (i < N) {
        int rp = row_ptr[i] + bsums[blockIdx.x];
        row_ptr[i] = rp;
        cursor[i] = rp;
        dis[i] = rsqrtf((float)cnt[i] + 1.0f);
    }
    if (i == 0) row_ptr[N] = E;
}

__global__ void k_fill(const int* __restrict__ src, const int* __restrict__ dst, int E,
                       int* __restrict__ cursor, int* __restrict__ csr_src) {
    int e = blockIdx.x * blockDim.x + threadIdx.x;
    if (e < E) {
        int pos = atomicAdd(&cursor[dst[e]], 1);
        csr_src[pos] = src[e];
    }
}

// ---------- coefficient precompute: Mnorm[j][c][o], j=0..31 ----------
__global__ void k_mnorm(const float* __restrict__ W2, float* __restrict__ M) {
    int idx = blockIdx.x * blockDim.x + threadIdx.x;
    if (idx >= 32 * 32 * 10) return;
    int o = idx % 10, c = (idx / 10) % 32, j = idx / 320;
    float v = 0.f;
    if (j >= 2 && j != 16) v += W2[(32 * j + c) * 10 + o];
    if (j <= 29 && j != 14) v -= W2[(32 * (j + 2) + c) * 10 + o];
    M[idx] = v;
}

// ---------- layer 0: x0 = mynorm(relu(x@W1+b1)); out init ----------
__global__ __launch_bounds__(256) void k_x0(
    const float* __restrict__ x, const float* __restrict__ W1, const float* __restrict__ b1,
    const float* __restrict__ W2, const float* __restrict__ b2, const float* __restrict__ M0,
    const float* __restrict__ dis, float* __restrict__ hs, float* __restrict__ out, int N)
{
    __shared__ float Ws[64 * 32];
    for (int i = threadIdx.x; i < 64 * 32; i += 256) Ws[i] = W1[i];
    __syncthreads();
    int wave = threadIdx.x >> 6;
    int lane = threadIdx.x & 63;
    int c = lane & 31, half = lane >> 5;
    int n = blockIdx.x * 4 + wave;
    if (n >= N) return;

    float xr = x[n * 64 + lane];                 // coalesced 256B row
    float acc = 0.f;
#pragma unroll
    for (int kk = 0; kk < 32; ++kk) {
        float xv = __shfl(xr, half * 32 + kk, 64);
        acc += xv * Ws[(half * 32 + kk) * 32 + c];
    }
    acc += shflx(acc, 32);                       // combine halves -> full 64-dot
    acc += b1[c];
    acc = fmaxf(acc, 0.f);
    // mynorm -> x0
    float mn = acc, mx = acc;
#pragma unroll
    for (int m = 1; m <= 16; m <<= 1) { mn = fminf(mn, shflx(mn, m)); mx = fmaxf(mx, shflx(mx, m)); }
    float x0 = 2.f * (acc - mn) / (mx - mn + 1e-8f) - 1.f;
    float dn = dis[n];
    if (half == 0) hs[n * 32 + c] = dn * x0;
    // norms[0] = mynorm(x0)
    mn = x0; mx = x0;
#pragma unroll
    for (int m = 1; m <= 16; m <<= 1) { mn = fminf(mn, shflx(mn, m)); mx = fmaxf(mx, shflx(mx, m)); }
    float n0 = 2.f * (x0 - mn) / (mx - mn + 1e-8f) - 1.f;
    // out[n] = b2 + x0@block0 + n0@Mnorm0
    float outv = 0.f;
#pragma unroll
    for (int o = 0; o < 10; ++o) {
        float t = x0 * W2[c * 10 + o] + n0 * M0[c * 10 + o];
#pragma unroll
        for (int m = 1; m <= 16; m <<= 1) t += shflx(t, m);
        if (lane == o) outv = t;
    }
    if (lane < 10) out[n * 10 + lane] = b2[lane] + outv;
}

// ---------- GCN layer j (xs index 1..31): fused gather + GEMM + out accum ----------
__global__ __launch_bounds__(256) void k_layer(
    const float* __restrict__ hs_in, float* __restrict__ hs_out,
    const float* __restrict__ dis, const int* __restrict__ row_ptr,
    const int* __restrict__ csr_src,
    const float* __restrict__ W, const float* __restrict__ b,
    const float* __restrict__ M, const float* __restrict__ W2raw,
    float* __restrict__ out, int N, int israw)
{
    __shared__ float Ws[32 * 32];
    for (int i = threadIdx.x; i < 1024; i += 256) Ws[i] = W[i];
    __syncthreads();
    int wave = threadIdx.x >> 6;
    int lane = threadIdx.x & 63;
    int c = lane & 31, half = lane >> 5;
    int n = blockIdx.x * 4 + wave;
    if (n >= N) return;

    float wreg[32];
#pragma unroll
    for (int k = 0; k < 32; ++k) wreg[k] = Ws[k * 32 + c];   // my W column

    int rs = row_ptr[n], re = row_ptr[n + 1];
    float acc = (half == 0) ? hs_in[n * 32 + c] : 0.f;       // self-loop term
    for (int e = rs + half; e < re; e += 2) {
        int s = csr_src[e];
        acc += hs_in[s * 32 + c];                            // coalesced 128B row gather
    }
    acc += shflx(acc, 32);                                   // combine halves
    float dn = dis[n];
    float g = dn * acc;                                      // g = dis*(sum + self)
    float xn = b[c];
#pragma unroll
    for (int k = 0; k < 32; ++k) xn += __shfl(g, k, 64) * wreg[k];   // x_next = g@W + b
    if (half == 0) hs_out[n * 32 + c] = dn * xn;
    // mynorm
    float mn = xn, mx = xn;
#pragma unroll
    for (int m = 1; m <= 16; m <<= 1) { mn = fminf(mn, shflx(mn, m)); mx = fmaxf(mx, shflx(mx, m)); }
    float nr = 2.f * (xn - mn) / (mx - mn + 1e-8f) - 1.f;
    // out accumulation
    float outv = 0.f;
#pragma unroll
    for (int o = 0; o < 10; ++o) {
        float t = nr * M[c * 10 + o];
        if (israw) t += xn * W2raw[c * 10 + o];
#pragma unroll
        for (int m = 1; m <= 16; m <<= 1) t += shflx(t, m);
        if (lane == o) outv = t;
    }
    if (lane < 10) out[n * 10 + lane] += outv;
}

extern "C" void kernel_launch(void* const* d_in, const int* in_sizes, int n_in,
                              void* d_out, int out_size, void* d_ws, size_t ws_size,
                              hipStream_t stream)
{
    const float* x  = (const float*)d_in[0];
    const int*   ei = (const int*)d_in[1];
    const float* W1 = (const float*)d_in[2];
    const float* b1 = (const float*)d_in[3];
    const float* Wc = (const float*)d_in[4];
    const float* bc = (const float*)d_in[5];
    const float* W2 = (const float*)d_in[6];
    const float* b2 = (const float*)d_in[7];
    float* out = (float*)d_out;

    const int N = in_sizes[0] / 64;
    const int E = in_sizes[1] / 2;
    const int* src = ei;
    const int* dst = ei + E;

    char* ws = (char*)d_ws;
    size_t off = 0;
    auto alloc = [&](size_t bytes) -> void* {
        void* p = ws + off;
        off = (off + bytes + 255) & ~size_t(255);
        return p;
    };
    int*   cnt     = (int*)alloc((size_t)N * 4);
    int*   row_ptr = (int*)alloc((size_t)(N + 1) * 4);
    int*   cursor  = (int*)alloc((size_t)N * 4);
    int*   bsums   = (int*)alloc(512 * 4);
    float* dis     = (float*)alloc((size_t)N * 4);
    int*   csr_src = (int*)alloc((size_t)E * 4);
    float* hs_a    = (float*)alloc((size_t)N * 32 * 4);
    float* hs_b    = (float*)alloc((size_t)N * 32 * 4);
    float* M       = (float*)alloc(32 * 32 * 10 * 4);

    hipMemsetAsync(cnt, 0, (size_t)N * 4, stream);
    const int eb = (E + 255) / 256;
    const int nb = (N + 255) / 256;          // 391 <= 512 for scan2
    k_hist<<<eb, 256, 0, stream>>>(dst, E, cnt);
    k_scan1<<<nb, 256, 0, stream>>>(cnt, N, row_ptr, bsums);
    k_scan2<<<1, 512, 0, stream>>>(bsums, nb);
    k_scan3<<<nb, 256, 0, stream>>>(row_ptr, bsums, cnt, N, E, cursor, dis);
    k_fill<<<eb, 256, 0, stream>>>(src, dst, E, cursor, csr_src);
    k_mnorm<<<(32 * 32 * 10 + 255) / 256, 256, 0, stream>>>(W2, M);

    const int gb = (N + 3) / 4;              // 1 wave per node, 4 nodes/block
    k_x0<<<gb, 256, 0, stream>>>(x, W1, b1, W2, b2, M, dis, hs_a, out, N);

    float* hin = hs_a; float* hout = hs_b;
    for (int j = 1; j <= 31; ++j) {
        int israw = (j == 1 || j == 16) ? 1 : 0;
        k_layer<<<gb, 256, 0, stream>>>(hin, hout, dis, row_ptr, csr_src,
                                        Wc + (size_t)(j - 1) * 1024,
                                        bc + (size_t)(j - 1) * 32,
                                        M + (size_t)j * 320,
                                        W2 + (size_t)j * 320,
                                        out, N, israw);
        float* t = hin; hin = hout; hout = t;
    }
}

// Round 2
// 3785.757 us; speedup vs baseline: 1.8705x; 1.8705x over previous
//
#include <hip/hip_runtime.h>

// SDGCN32: 31-layer GCN, N=100k nodes, E=3.2M edges, F=32.
//  - hs = dis*h carried between layers; layer = gather(hs) -> *dis -> @W + b
//  - CSR (by dst) built once per launch
//  - out accumulated online per layer: out += mynorm(x_j)@Mn_j (+ raw x_j@Rw_j for j in {1,16})
//  - k_layer lane map: slot=lane>>3 walks every-8th edge, q=lane&7 owns channels 4q..4q+3 (float4)
//    -> 16 float4 gathers in flight per wave (latency-bound fix vs scalar 2-in-flight)

__device__ __forceinline__ float shflx(float v, int m) { return __shfl_xor(v, m, 64); }

// ---------- CSR build ----------
__global__ void k_hist(const int* __restrict__ dst, int E, int* __restrict__ cnt) {
    int e = blockIdx.x * blockDim.x + threadIdx.x;
    if (e < E) atomicAdd(&cnt[dst[e]], 1);
}

__global__ void k_scan1(const int* __restrict__ cnt, int N, int* __restrict__ row_ptr,
                        int* __restrict__ bsums) {
    __shared__ int s[256];
    int i = blockIdx.x * 256 + threadIdx.x;
    int v = (i < N) ? cnt[i] : 0;
    s[threadIdx.x] = v;
    __syncthreads();
    for (int off = 1; off < 256; off <<= 1) {
        int t = (threadIdx.x >= off) ? s[threadIdx.x - off] : 0;
        __syncthreads();
        s[threadIdx.x] += t;
        __syncthreads();
    }
    int incl = s[threadIdx.x];
    if (i < N) row_ptr[i] = incl - v;
    if (threadIdx.x == 255) bsums[blockIdx.x] = incl;
}

__global__ void k_scan2(int* __restrict__ bsums, int nb) {
    __shared__ int s[512];
    int v = (threadIdx.x < nb) ? bsums[threadIdx.x] : 0;
    s[threadIdx.x] = v;
    __syncthreads();
    for (int off = 1; off < 512; off <<= 1) {
        int t = (threadIdx.x >= off) ? s[threadIdx.x - off] : 0;
        __syncthreads();
        s[threadIdx.x] += t;
        __syncthreads();
    }
    if (threadIdx.x < nb) bsums[threadIdx.x] = s[threadIdx.x] - v;
}

__global__ void k_scan3(int* __restrict__ row_ptr, const int* __restrict__ bsums,
                        const int* __restrict__ cnt, int N, int E,
                        int* __restrict__ cursor, float* __restrict__ dis) {
    int i = blockIdx.x * 256 + threadIdx.x;
    if (i < N) {
        int rp = row_ptr[i] + bsums[blockIdx.x];
        row_ptr[i] = rp;
        cursor[i] = rp;
        dis[i] = rsqrtf((float)cnt[i] + 1.0f);
    }
    if (i == 0) row_ptr[N] = E;
}

__global__ void k_fill(const int* __restrict__ src, const int* __restrict__ dst, int E,
                       int* __restrict__ cursor, int* __restrict__ csr_src) {
    int e = blockIdx.x * blockDim.x + threadIdx.x;
    if (e < E) {
        int pos = atomicAdd(&cursor[dst[e]], 1);
        csr_src[pos] = src[e];
    }
}

// ---------- coefficients, layout [j][o][c] ----------
// Mn[j][o][c] = [j>=2 && j!=16]*W2[(32j+c),o] - [j<=29 && j!=14]*W2[(32(j+2)+c),o]
// Rw[j][o][c] = [j in {0,1,16}]*W2[(32j+c),o]
__global__ void k_mnorm(const float* __restrict__ W2, float* __restrict__ Mn,
                        float* __restrict__ Rw) {
    int idx = blockIdx.x * blockDim.x + threadIdx.x;
    if (idx >= 32 * 32 * 10) return;
    int c = idx % 32, o = (idx / 32) % 10, j = idx / 320;
    float v = 0.f;
    if (j >= 2 && j != 16) v += W2[(32 * j + c) * 10 + o];
    if (j <= 29 && j != 14) v -= W2[(32 * (j + 2) + c) * 10 + o];
    Mn[idx] = v;
    Rw[idx] = (j == 0 || j == 1 || j == 16) ? W2[(32 * j + c) * 10 + o] : 0.f;
}

// ---------- layer 0: x0 = mynorm(relu(x@W1+b1)); out init ----------
__global__ __launch_bounds__(256) void k_x0(
    const float* __restrict__ x, const float* __restrict__ W1, const float* __restrict__ b1,
    const float* __restrict__ W2, const float* __restrict__ b2, const float* __restrict__ M0,
    const float* __restrict__ dis, float* __restrict__ hs, float* __restrict__ out, int N)
{
    __shared__ float Ws[64 * 32];
    for (int i = threadIdx.x; i < 64 * 32; i += 256) Ws[i] = W1[i];
    __syncthreads();
    int wave = threadIdx.x >> 6;
    int lane = threadIdx.x & 63;
    int c = lane & 31, half = lane >> 5;
    int n = blockIdx.x * 4 + wave;
    if (n >= N) return;

    float xr = x[n * 64 + lane];
    float acc = 0.f;
#pragma unroll
    for (int kk = 0; kk < 32; ++kk) {
        float xv = __shfl(xr, half * 32 + kk, 64);
        acc += xv * Ws[(half * 32 + kk) * 32 + c];
    }
    acc += shflx(acc, 32);
    acc += b1[c];
    acc = fmaxf(acc, 0.f);
    float mn = acc, mx = acc;
#pragma unroll
    for (int m = 1; m <= 16; m <<= 1) { mn = fminf(mn, shflx(mn, m)); mx = fmaxf(mx, shflx(mx, m)); }
    float x0 = 2.f * (acc - mn) / (mx - mn + 1e-8f) - 1.f;
    float dn = dis[n];
    if (half == 0) hs[n * 32 + c] = dn * x0;
    mn = x0; mx = x0;
#pragma unroll
    for (int m = 1; m <= 16; m <<= 1) { mn = fminf(mn, shflx(mn, m)); mx = fmaxf(mx, shflx(mx, m)); }
    float n0 = 2.f * (x0 - mn) / (mx - mn + 1e-8f) - 1.f;
    float outv = 0.f;
#pragma unroll
    for (int o = 0; o < 10; ++o) {
        float t = x0 * W2[c * 10 + o] + n0 * M0[o * 32 + c];
#pragma unroll
        for (int m = 1; m <= 16; m <<= 1) t += shflx(t, m);
        if (lane == o) outv = t;
    }
    if (lane < 10) out[n * 10 + lane] = b2[lane] + outv;
}

// ---------- GCN layer j: fused gather + GEMM + mynorm + out accum ----------
__global__ __launch_bounds__(256) void k_layer(
    const float4* __restrict__ hs_in, float4* __restrict__ hs_out,
    const float* __restrict__ dis, const int* __restrict__ row_ptr,
    const int* __restrict__ csr_src,
    const float* __restrict__ W, const float* __restrict__ b,
    const float* __restrict__ Mn, const float* __restrict__ Rw,
    float* __restrict__ out, int N, int israw)
{
    __shared__ float Ws[1024];   // W [k][c] row-major
    __shared__ float bs[32];
    __shared__ float Ms[320];    // Mn_j [o][c]
    __shared__ float Rs[320];    // Rw_j [o][c]
    for (int i = threadIdx.x; i < 1024; i += 256) Ws[i] = W[i];
    for (int i = threadIdx.x; i < 320; i += 256) { Ms[i] = Mn[i]; Rs[i] = Rw[i]; }
    if (threadIdx.x < 32) bs[threadIdx.x] = b[threadIdx.x];
    __syncthreads();

    int lane = threadIdx.x & 63;
    int q = lane & 7;            // channel quad: c = 4q..4q+3
    int slot = lane >> 3;        // edge slot 0..7
    int n = blockIdx.x * 4 + (threadIdx.x >> 6);
    if (n >= N) return;

    int rs = row_ptr[n], re = row_ptr[n + 1];

    float4 a0 = make_float4(0.f, 0.f, 0.f, 0.f);
    float4 a1 = make_float4(0.f, 0.f, 0.f, 0.f);
    if (slot == 0) a0 = hs_in[n * 8 + q];                     // self-loop term
    int e = rs + slot;
    for (; e + 8 < re; e += 16) {                             // 16 edges in flight/wave
        int s0 = csr_src[e], s1 = csr_src[e + 8];
        float4 v0 = hs_in[s0 * 8 + q];
        float4 v1 = hs_in[s1 * 8 + q];
        a0.x += v0.x; a0.y += v0.y; a0.z += v0.z; a0.w += v0.w;
        a1.x += v1.x; a1.y += v1.y; a1.z += v1.z; a1.w += v1.w;
    }
    if (e < re) {
        int s = csr_src[e];
        float4 v = hs_in[s * 8 + q];
        a0.x += v.x; a0.y += v.y; a0.z += v.z; a0.w += v.w;
    }
    a0.x += a1.x; a0.y += a1.y; a0.z += a1.z; a0.w += a1.w;
    // reduce over slot bits (3,4,5) -> all lanes hold full sum for channels 4q..4q+3
#pragma unroll
    for (int m = 8; m <= 32; m <<= 1) {
        a0.x += shflx(a0.x, m); a0.y += shflx(a0.y, m);
        a0.z += shflx(a0.z, m); a0.w += shflx(a0.w, m);
    }
    float dn = dis[n];
    float4 g = make_float4(dn * a0.x, dn * a0.y, dn * a0.z, dn * a0.w);

    // GEMM: slot s handles k = 4s..4s+3; partial xn over those k; reduce over slots
    float gx = __shfl(g.x, slot, 64);   // g[4*slot+0]  (lane 'slot' has q==slot)
    float gy = __shfl(g.y, slot, 64);
    float gz = __shfl(g.z, slot, 64);
    float gw = __shfl(g.w, slot, 64);
    const float4* W4 = (const float4*)Ws;
    int k0 = slot * 4;
    float4 xn = make_float4(0.f, 0.f, 0.f, 0.f);
    {
        float4 w0 = W4[(k0 + 0) * 8 + q];
        float4 w1 = W4[(k0 + 1) * 8 + q];
        float4 w2 = W4[(k0 + 2) * 8 + q];
        float4 w3 = W4[(k0 + 3) * 8 + q];
        xn.x = gx * w0.x + gy * w1.x + gz * w2.x + gw * w3.x;
        xn.y = gx * w0.y + gy * w1.y + gz * w2.y + gw * w3.y;
        xn.z = gx * w0.z + gy * w1.z + gz * w2.z + gw * w3.z;
        xn.w = gx * w0.w + gy * w1.w + gz * w2.w + gw * w3.w;
    }
#pragma unroll
    for (int m = 8; m <= 32; m <<= 1) {
        xn.x += shflx(xn.x, m); xn.y += shflx(xn.y, m);
        xn.z += shflx(xn.z, m); xn.w += shflx(xn.w, m);
    }
    const float4* B4 = (const float4*)bs;
    float4 bb = B4[q];
    xn.x += bb.x; xn.y += bb.y; xn.z += bb.z; xn.w += bb.w;

    if (slot == 0)
        hs_out[n * 8 + q] = make_float4(dn * xn.x, dn * xn.y, dn * xn.z, dn * xn.w);

    // mynorm: min/max over 4 local channels, then over q bits (0,1,2)
    float mn = fminf(fminf(xn.x, xn.y), fminf(xn.z, xn.w));
    float mx = fmaxf(fmaxf(xn.x, xn.y), fmaxf(xn.z, xn.w));
#pragma unroll
    for (int m = 1; m <= 4; m <<= 1) { mn = fminf(mn, shflx(mn, m)); mx = fmaxf(mx, shflx(mx, m)); }
    float sc = 2.f / (mx - mn + 1e-8f);
    float4 nr = make_float4((xn.x - mn) * sc - 1.f, (xn.y - mn) * sc - 1.f,
                            (xn.z - mn) * sc - 1.f, (xn.w - mn) * sc - 1.f);

    // out accumulation: t[o] = nr . Mn[o][:] (+ xn . Rw[o][:])
    const float4* M4 = (const float4*)Ms;
    const float4* R4 = (const float4*)Rs;
    float outv = 0.f;
#pragma unroll
    for (int o = 0; o < 10; ++o) {
        float4 m4 = M4[o * 8 + q];
        float t = nr.x * m4.x + nr.y * m4.y + nr.z * m4.z + nr.w * m4.w;
        if (israw) {
            float4 r4 = R4[o * 8 + q];
            t += xn.x * r4.x + xn.y * r4.y + xn.z * r4.z + xn.w * r4.w;
        }
        t += shflx(t, 1); t += shflx(t, 2); t += shflx(t, 4);
        if (lane == o) outv = t;
    }
    if (lane < 10) out[n * 10 + lane] += outv;
}

extern "C" void kernel_launch(void* const* d_in, const int* in_sizes, int n_in,
                              void* d_out, int out_size, void* d_ws, size_t ws_size,
                              hipStream_t stream)
{
    const float* x  = (const float*)d_in[0];
    const int*   ei = (const int*)d_in[1];
    const float* W1 = (const float*)d_in[2];
    const float* b1 = (const float*)d_in[3];
    const float* Wc = (const float*)d_in[4];
    const float* bc = (const float*)d_in[5];
    const float* W2 = (const float*)d_in[6];
    const float* b2 = (const float*)d_in[7];
    float* out = (float*)d_out;

    const int N = in_sizes[0] / 64;
    const int E = in_sizes[1] / 2;
    const int* src = ei;
    const int* dst = ei + E;

    char* ws = (char*)d_ws;
    size_t off = 0;
    auto alloc = [&](size_t bytes) -> void* {
        void* p = ws + off;
        off = (off + bytes + 255) & ~size_t(255);
        return p;
    };
    int*   cnt     = (int*)alloc((size_t)N * 4);
    int*   row_ptr = (int*)alloc((size_t)(N + 1) * 4);
    int*   cursor  = (int*)alloc((size_t)N * 4);
    int*   bsums   = (int*)alloc(512 * 4);
    float* dis     = (float*)alloc((size_t)N * 4);
    int*   csr_src = (int*)alloc((size_t)E * 4);
    float* hs_a    = (float*)alloc((size_t)N * 32 * 4);
    float* hs_b    = (float*)alloc((size_t)N * 32 * 4);
    float* Mn      = (float*)alloc(32 * 32 * 10 * 4);
    float* Rw      = (float*)alloc(32 * 32 * 10 * 4);

    hipMemsetAsync(cnt, 0, (size_t)N * 4, stream);
    const int eb = (E + 255) / 256;
    const int nb = (N + 255) / 256;          // 391 <= 512 for scan2
    k_hist<<<eb, 256, 0, stream>>>(dst, E, cnt);
    k_scan1<<<nb, 256, 0, stream>>>(cnt, N, row_ptr, bsums);
    k_scan2<<<1, 512, 0, stream>>>(bsums, nb);
    k_scan3<<<nb, 256, 0, stream>>>(row_ptr, bsums, cnt, N, E, cursor, dis);
    k_fill<<<eb, 256, 0, stream>>>(src, dst, E, cursor, csr_src);
    k_mnorm<<<(32 * 32 * 10 + 255) / 256, 256, 0, stream>>>(W2, Mn, Rw);

    const int gb = (N + 3) / 4;              // 1 wave per node
    k_x0<<<gb, 256, 0, stream>>>(x, W1, b1, W2, b2, Mn, dis, hs_a, out, N);

    float* hin = hs_a; float* hout = hs_b;
    for (int j = 1; j <= 31; ++j) {
        int israw = (j == 1 || j == 16) ? 1 : 0;
        k_layer<<<gb, 256, 0, stream>>>((const float4*)hin, (float4*)hout, dis, row_ptr,
                                        csr_src,
                                        Wc + (size_t)(j - 1) * 1024,
                                        bc + (size_t)(j - 1) * 32,
                                        Mn + (size_t)j * 320,
                                        Rw + (size_t)j * 320,
                                        out, N, israw);
        float* t = hin; hin = hout; hout = t;
    }
}